// Round 5
// baseline (939.783 us; speedup 1.0000x reference)
//
#include <hip/hip_runtime.h>

#define EPS_C 0.01f
#define NU    128
#define DIN   64
#define COUT  10

typedef float    f32x4 __attribute__((ext_vector_type(4)));
typedef _Float16 f16x4 __attribute__((ext_vector_type(4)));

#define MFMA16(A, B, C) __builtin_amdgcn_mfma_f32_16x16x16f16((A), (B), (C), 0, 0, 0)

// ---------------- pre-pass: x fp32 -> f16 B-operand fragment layout ----------------
// ws element (f16x4 units): idx = ((g*T + t)*4 + kt)*64 + lane
// lane L = lid + 16*quad holds x^T[d = 16*kt + 4*quad + j][batch = g*16 + lid], j=0..3
__global__ __launch_bounds__(256)
void xprep(const float* __restrict__ x, _Float16* __restrict__ wsx, int T)
{
    const int g   = blockIdx.x / T;
    const int t   = blockIdx.x % T;
    const int kt  = threadIdx.x >> 6;
    const int L   = threadIdx.x & 63;
    const int lid = L & 15, quad = L >> 4;
    const float4 v = *(const float4*)(x + ((size_t)(g * 16 + lid) * T + t) * DIN
                                        + kt * 16 + quad * 4);
    f16x4 o;
    o[0] = (_Float16)v.x; o[1] = (_Float16)v.y;
    o[2] = (_Float16)v.z; o[3] = (_Float16)v.w;
    *(f16x4*)(wsx + ((((size_t)g * T + t) * 4 + kt) * 64 + L) * 4) = o;
}

// ---------------- recurrence: transposed form, h lives in registers ----------------
// Per block: 16 batch rows (batch = n = lid of every MFMA). 4 waves; wave w owns
// output rows u in [32w, 32w+32) = m-tiles {2w, 2w+1}.
// mfma_f32_16x16x16f16 layouts:
//   A-op: A[m = lid][k = 4*quad + j]     B-op: B[k = 4*quad + j][n = lid]
//   D   : D[row = 4*quad + reg][col = lid]
// => D layout of h^T(t+1) tile mt IS the B-op layout for k-tile kt=mt: the
//    recurrence state never leaves registers except a 6-fragment LDS exchange.
template<int USE_WS>
__global__ __launch_bounds__(256, 1)
void rnn_core(const float* __restrict__ x, const _Float16* __restrict__ wsx,
              const float* __restrict__ E_w, const float* __restrict__ E_b,
              const float* __restrict__ B_p, const float* __restrict__ C_p,
              const float* __restrict__ D_w, const float* __restrict__ D_b,
              float* __restrict__ out, int T)
{
    const int tid  = threadIdx.x;
    const int lane = tid & 63;
    const int w    = tid >> 6;     // wave 0..3
    const int lid  = lane & 15;
    const int quad = lane >> 4;
    const int g    = blockIdx.x;   // batch group (16 rows)

    __shared__ _Float16 hbuf[2][8][64][4];   // [parity][kt][lane][j]  8 KB
    __shared__ float    hfin[16][NU + 4];    // final h, padded        8.4 KB

    // ---- one-time weight fragments (A-operand form) ----
    // A = B_p - 0.6*B_p^T - 0.01*I ; we need A^T tiles: AT(mt,kt)[lane][j] =
    // A[k_g][m_g] with k_g = 16kt+4quad+j (u_in), m_g = 16mt+lid (u_out).
    f16x4 AT[2][8], WT[2][8], EF[2][4];
    float eb[2][4];
    #pragma unroll
    for (int mtl = 0; mtl < 2; ++mtl) {
        const int m = (w * 2 + mtl) * 16 + lid;
        #pragma unroll
        for (int kt = 0; kt < 8; ++kt) {
            #pragma unroll
            for (int j = 0; j < 4; ++j) {
                const int k  = kt * 16 + quad * 4 + j;
                const float dg = (k == m) ? 0.01f : 0.0f;
                AT[mtl][kt][j] = (_Float16)(B_p[k * NU + m] - 0.6f * B_p[m * NU + k] - dg);
                WT[mtl][kt][j] = (_Float16)(C_p[k * NU + m] - 0.6f * C_p[m * NU + k] - dg);
            }
        }
        #pragma unroll
        for (int kt = 0; kt < 4; ++kt)
            #pragma unroll
            for (int j = 0; j < 4; ++j)
                EF[mtl][kt][j] = (_Float16)E_w[m * DIN + kt * 16 + quad * 4 + j];
        #pragma unroll
        for (int r = 0; r < 4; ++r)
            eb[mtl][r] = E_b[(w * 2 + mtl) * 16 + quad * 4 + r];
    }

    // ---- state init ----
    f16x4 hn[2];   // own new-h fragments (k-tiles 2w, 2w+1), f16
    f32x4 hf[2];   // fp32 master h (same index mapping)
    #pragma unroll
    for (int i = 0; i < 2; ++i) {
        hn[i][0] = hn[i][1] = hn[i][2] = hn[i][3] = (_Float16)0.0f;
        hf[i][0] = hf[i][1] = hf[i][2] = hf[i][3] = 0.0f;
    }
    // zero parity-0 buffer (4096 B) so t=0 reads zeros
    ((float4*)&hbuf[0][0][0][0])[tid] = (float4){0.f, 0.f, 0.f, 0.f};
    __syncthreads();

    // ---- x prefetch (depth 4 steps) ----
    const _Float16* xw_base = wsx + (size_t)g * T * 1024;   // 1024 halves per t
    const float*    xf_base = x + (size_t)(g * 16 + lid) * T * DIN + quad * 4;
    f16x4  xq [4][4];
    float4 xqf[4][4];
    #pragma unroll
    for (int i = 0; i < 4; ++i) {
        #pragma unroll
        for (int kt = 0; kt < 4; ++kt) {
            if (USE_WS)
                xq[i][kt]  = *(const f16x4*)(xw_base + ((size_t)i * 4 + kt) * 256 + lane * 4);
            else
                xqf[i][kt] = *(const float4*)(xf_base + (size_t)i * DIN + kt * 16);
        }
    }

    for (int t0 = 0; t0 < T; t0 += 4) {
        #pragma unroll
        for (int i = 0; i < 4; ++i) {
            const int p = i & 1;   // == t&1 (t0 multiple of 4)

            // gather this step's h fragments: own from regs, 6 others from LDS
            f16x4 hB[8];
            #pragma unroll
            for (int kt = 0; kt < 8; ++kt) {
                f16x4 ld = *(const f16x4*)&hbuf[p][kt][lane][0];
                hB[kt] = ((kt >> 1) == w) ? hn[kt & 1] : ld;
            }

            // this step's x fragments (already in regs)
            f16x4 xf[4];
            #pragma unroll
            for (int kt = 0; kt < 4; ++kt) {
                if (USE_WS) {
                    xf[kt] = xq[i][kt];
                } else {
                    float4 v = xqf[i][kt];
                    xf[kt][0] = (_Float16)v.x; xf[kt][1] = (_Float16)v.y;
                    xf[kt][2] = (_Float16)v.z; xf[kt][3] = (_Float16)v.w;
                }
            }
            // refill slot i for step t0+i+4 (clamped; tail loads unused)
            {
                int tn = t0 + i + 4; if (tn >= T) tn = T - 1;
                #pragma unroll
                for (int kt = 0; kt < 4; ++kt) {
                    if (USE_WS)
                        xq[i][kt]  = *(const f16x4*)(xw_base + ((size_t)tn * 4 + kt) * 256 + lane * 4);
                    else
                        xqf[i][kt] = *(const float4*)(xf_base + (size_t)tn * DIN + kt * 16);
                }
            }

            // ---- MFMAs: Y^T = A^T h^T ; Arg^T = W^T h^T + E x^T + E_b ----
            f32x4 ya0 = {0.f, 0.f, 0.f, 0.f};
            f32x4 ya1 = {0.f, 0.f, 0.f, 0.f};
            f32x4 wa0 = {eb[0][0], eb[0][1], eb[0][2], eb[0][3]};
            f32x4 wa1 = {eb[1][0], eb[1][1], eb[1][2], eb[1][3]};
            #pragma unroll
            for (int kt = 0; kt < 4; ++kt) {   // E terms first: x is reg-resident
                wa0 = MFMA16(EF[0][kt], xf[kt], wa0);
                wa1 = MFMA16(EF[1][kt], xf[kt], wa1);
            }
            #pragma unroll
            for (int kt = 0; kt < 8; ++kt) {
                ya0 = MFMA16(AT[0][kt], hB[kt], ya0);
                ya1 = MFMA16(AT[1][kt], hB[kt], ya1);
                wa0 = MFMA16(WT[0][kt], hB[kt], wa0);
                wa1 = MFMA16(WT[1][kt], hB[kt], wa1);
            }

            // ---- epilogue: h += eps*(Y + tanh(Arg)); D layout == next B layout ----
            #pragma unroll
            for (int mtl = 0; mtl < 2; ++mtl) {
                const f32x4 ya = mtl ? ya1 : ya0;
                const f32x4 wa = mtl ? wa1 : wa0;
                f16x4 nh;
                #pragma unroll
                for (int r = 0; r < 4; ++r) {
                    const float arg = wa[r];
                    const float e2  = __expf(2.0f * arg);
                    const float th  = 1.0f - 2.0f / (e2 + 1.0f);   // tanh, inf-safe
                    const float hv  = hf[mtl][r] + EPS_C * (ya[r] + th);
                    hf[mtl][r] = hv;
                    nh[r] = (_Float16)hv;
                }
                hn[mtl] = nh;
                *(f16x4*)&hbuf[1 - p][2 * w + mtl][lane][0] = nh;   // stride-1, conflict-free
            }
            __syncthreads();   // one barrier per step (double-buffered exchange)
        }
    }

    // ---- final: stash h to LDS, then 160 threads do the small output GEMM ----
    #pragma unroll
    for (int mtl = 0; mtl < 2; ++mtl)
        #pragma unroll
        for (int r = 0; r < 4; ++r)
            hfin[lid][(w * 2 + mtl) * 16 + quad * 4 + r] = hf[mtl][r];
    __syncthreads();

    if (tid < 16 * COUT) {
        const int r = tid / COUT;
        const int c = tid - r * COUT;
        float acc = D_b[c];
        #pragma unroll 8
        for (int u = 0; u < NU; ++u)
            acc = fmaf(hfin[r][u], D_w[c * NU + u], acc);
        out[((size_t)g * 16 + r) * COUT + c] = acc;
    }
}

extern "C" void kernel_launch(void* const* d_in, const int* in_sizes, int n_in,
                              void* d_out, int out_size, void* d_ws, size_t ws_size,
                              hipStream_t stream)
{
    const float* x   = (const float*)d_in[0];
    const float* E_w = (const float*)d_in[1];
    const float* E_b = (const float*)d_in[2];
    const float* B_p = (const float*)d_in[3];
    const float* C_p = (const float*)d_in[4];
    const float* D_w = (const float*)d_in[5];
    const float* D_b = (const float*)d_in[6];
    float* out = (float*)d_out;

    const int B  = out_size / COUT;            // 512
    const int T  = in_sizes[0] / (B * DIN);    // 1024
    const int NB = B / 16;                     // 32 blocks

    const size_t need = (size_t)B * T * DIN * sizeof(_Float16);  // 67 MB
    if (ws_size >= need) {
        _Float16* wsx = (_Float16*)d_ws;
        xprep<<<NB * T, 256, 0, stream>>>(x, wsx, T);
        rnn_core<1><<<NB, 256, 0, stream>>>(x, wsx, E_w, E_b, B_p, C_p, D_w, D_b, out, T);
    } else {
        rnn_core<0><<<NB, 256, 0, stream>>>(x, nullptr, E_w, E_b, B_p, C_p, D_w, D_b, out, T);
    }
}

// Round 6
// 882.304 us; speedup vs baseline: 1.0651x; 1.0651x over previous
//
#include <hip/hip_runtime.h>

#define EPS_C 0.01f
#define NU    128
#define DIN   64
#define COUT  10

typedef float    f32x4 __attribute__((ext_vector_type(4)));
typedef _Float16 f16x4 __attribute__((ext_vector_type(4)));
typedef _Float16 f16x8 __attribute__((ext_vector_type(8)));

#define MFMA32(A, B, C) __builtin_amdgcn_mfma_f32_16x16x32_f16((A), (B), (C), 0, 0, 0)

// Transposed recurrence h^T(t+1) = h^T + eps*(A^T h^T + tanh(W^T h^T + z^T)),
// batch along MFMA n-dim (16 rows/block, 32 blocks). 4 waves; wave w owns
// units u in [32w, 32w+32) = m-tiles {2w, 2w+1}.
// mfma_f32_16x16x32_f16 layouts (HW-verified round 3):
//   A-op: A[m = lane&15][k = quad*8 + j]   (j=0..7)
//   B-op: B[k = quad*8 + j][n = lane&15]
//   D   : D[row = quad*4 + reg][col = lane&15]
// h exchange via LDS does the D->B shuffle: value u=16mt+4q+r, b=lid lands at
// hbuf[u>>5][((u>>3)&3)*16 + b][u&7]; reads are linear ds_read_b128.
// z(t+1) = E x(t+1) + E_b computed during step t (separate accumulator, off the
// critical path); x staged per-16-step chunk into double-buffered LDS.
__global__ __launch_bounds__(256, 1)
void rnn_core(const float* __restrict__ x,
              const float* __restrict__ E_w, const float* __restrict__ E_b,
              const float* __restrict__ B_p, const float* __restrict__ C_p,
              const float* __restrict__ D_w, const float* __restrict__ D_b,
              float* __restrict__ out, int T)
{
    const int tid  = threadIdx.x;
    const int lane = tid & 63;
    const int w    = tid >> 6;     // wave 0..3
    const int lid  = lane & 15;
    const int q    = lane >> 4;
    const int g    = blockIdx.x;   // batch group (16 rows)

    // xs[buf]: 16 steps of x in B-frag layout: [t16][kt(2)][lane64][8 halves]
    __shared__ _Float16 xs[2][16 * 2 * 64 * 8];   // 2 x 32 KB
    __shared__ _Float16 hbuf[2][4][64][8];        // [parity][kt][lane][j] 8 KB
    __shared__ float    hfin[16][NU + 4];

    // ---- one-time weight fragments ----
    // AT[mtl][kt] elem j = A[k][m],  k = 32kt+8q+j,  m = 16(2w+mtl)+lid
    f16x8 AT[2][4], WT[2][4], EF[2][2];
    f32x4 ebv[2];
    #pragma unroll
    for (int mtl = 0; mtl < 2; ++mtl) {
        const int m = (w * 2 + mtl) * 16 + lid;
        #pragma unroll
        for (int kt = 0; kt < 4; ++kt) {
            f16x8 fa, fw;
            #pragma unroll
            for (int j = 0; j < 8; ++j) {
                const int k  = kt * 32 + q * 8 + j;
                const float dg = (k == m) ? 0.01f : 0.0f;
                fa[j] = (_Float16)(B_p[k * NU + m] - 0.6f * B_p[m * NU + k] - dg);
                fw[j] = (_Float16)(C_p[k * NU + m] - 0.6f * C_p[m * NU + k] - dg);
            }
            AT[mtl][kt] = fa;  WT[mtl][kt] = fw;
        }
        #pragma unroll
        for (int kt = 0; kt < 2; ++kt) {
            f16x8 fe;
            #pragma unroll
            for (int j = 0; j < 8; ++j)
                fe[j] = (_Float16)E_w[m * DIN + kt * 32 + q * 8 + j];
            EF[mtl][kt] = fe;
        }
        #pragma unroll
        for (int r = 0; r < 4; ++r)
            ebv[mtl][r] = E_b[(w * 2 + mtl) * 16 + q * 4 + r];
    }

    // ---- zero parity-0 h buffer (4 KB = 256 x 16B) ----
    ((float4*)&hbuf[0][0][0][0])[tid] = (float4){0.f, 0.f, 0.f, 0.f};

    // ---- x chunk staging ----
    // loader mapping: bb = batch row, s = d-quad (d = 4s..4s+3)
    const int bb = tid & 15;
    const int s  = tid >> 4;
    const float* xrow = x + ((size_t)(g * 16 + bb) * T) * DIN + s * 4;
    // write target: xs[buf][ (t*2 + (s>>3))*64 + ((s>>1)&3)*16 + bb ][ (s&1)*4 .. ]
    const int wbyte = (((s >> 3) * 64) + (((s >> 1) & 3) * 16) + bb) * 16 + (s & 1) * 8;

    float4 xg[16];
    #pragma unroll
    for (int i = 0; i < 16; ++i)
        xg[i] = *(const float4*)(xrow + (size_t)i * DIN);

#define STAGE_WRITE(BUF)                                                      \
    {                                                                         \
        char* base = (char*)&xs[(BUF)][0];                                    \
        _Pragma("unroll")                                                     \
        for (int i2 = 0; i2 < 16; ++i2) {                                     \
            float4 v = xg[i2];                                                \
            f16x4 h4;                                                         \
            h4[0] = (_Float16)v.x; h4[1] = (_Float16)v.y;                     \
            h4[2] = (_Float16)v.z; h4[3] = (_Float16)v.w;                     \
            *(f16x4*)(base + i2 * 2048 + wbyte) = h4;                         \
        }                                                                     \
    }

    STAGE_WRITE(0)
    __syncthreads();

    // ---- state init: h = 0, z_cur = z(0) ----
    f32x4 hf[2] = {{0.f, 0.f, 0.f, 0.f}, {0.f, 0.f, 0.f, 0.f}};
    f32x4 zc[2];
    {
        f16x8 x0 = *(const f16x8*)((char*)&xs[0][0] + (0 * 64 + lane) * 16);
        f16x8 x1 = *(const f16x8*)((char*)&xs[0][0] + (1 * 64 + lane) * 16);
        zc[0] = ebv[0];  zc[1] = ebv[1];
        zc[0] = MFMA32(EF[0][0], x0, zc[0]);
        zc[1] = MFMA32(EF[1][0], x0, zc[1]);
        zc[0] = MFMA32(EF[0][1], x1, zc[0]);
        zc[1] = MFMA32(EF[1][1], x1, zc[1]);
    }

    const int nch = T >> 4;   // 64 chunks of 16 steps
    for (int c = 0; c < nch; ++c) {
        if (c + 1 < nch) {
            const float* xr2 = xrow + (size_t)(c + 1) * 16 * DIN;
            #pragma unroll
            for (int i = 0; i < 16; ++i)
                xg[i] = *(const float4*)(xr2 + (size_t)i * DIN);
        }
        #pragma unroll 2
        for (int i = 0; i < 16; ++i) {
            const int t  = c * 16 + i;
            const int p  = i & 1;
            const int np = p ^ 1;

            // h B-frags for this step (linear, conflict-free)
            f16x8 hB[4];
            #pragma unroll
            for (int kt = 0; kt < 4; ++kt)
                hB[kt] = *(const f16x8*)((char*)&hbuf[p][0][0][0] + (kt * 64 + lane) * 16);

            // x B-frags for t+1 (for z_next; off critical path)
            int tt = t + 1; if (tt >= T) tt = T - 1;
            const int  it   = tt & 15;
            char*      xb   = (char*)&xs[(tt >> 4) & 1][0];
            f16x8 xfA = *(const f16x8*)(xb + ((it * 2 + 0) * 64 + lane) * 16);
            f16x8 xfB = *(const f16x8*)(xb + ((it * 2 + 1) * 64 + lane) * 16);

            // ---- on-path MFMAs: depth-4 chains, 4-wide interleave ----
            f32x4 ya0 = {0.f, 0.f, 0.f, 0.f};
            f32x4 ya1 = {0.f, 0.f, 0.f, 0.f};
            f32x4 wa0 = zc[0];
            f32x4 wa1 = zc[1];
            #pragma unroll
            for (int kt = 0; kt < 4; ++kt) {
                ya0 = MFMA32(AT[0][kt], hB[kt], ya0);
                ya1 = MFMA32(AT[1][kt], hB[kt], ya1);
                wa0 = MFMA32(WT[0][kt], hB[kt], wa0);
                wa1 = MFMA32(WT[1][kt], hB[kt], wa1);
            }
            // z(t+1): off-path
            f32x4 zn0 = ebv[0], zn1 = ebv[1];
            zn0 = MFMA32(EF[0][0], xfA, zn0);
            zn1 = MFMA32(EF[1][0], xfA, zn1);
            zn0 = MFMA32(EF[0][1], xfB, zn0);
            zn1 = MFMA32(EF[1][1], xfB, zn1);

            // ---- epilogue: h += eps*(ya + tanh(wa)); write D->B shuffled ----
            char* hwp = (char*)&hbuf[np][w][0][0];
            #pragma unroll
            for (int mtl = 0; mtl < 2; ++mtl) {
                const f32x4 ya = mtl ? ya1 : ya0;
                const f32x4 wa = mtl ? wa1 : wa0;
                f16x4 nh;
                #pragma unroll
                for (int r = 0; r < 4; ++r) {
                    const float arg = wa[r];
                    const float e2  = __expf(2.0f * arg);
                    const float th  = 1.0f - 2.0f / (e2 + 1.0f);   // tanh, inf-safe
                    const float hv  = hf[mtl][r] + EPS_C * (ya[r] + th);
                    hf[mtl][r] = hv;
                    nh[r] = (_Float16)hv;
                }
                const int row = (mtl * 2 + (q >> 1)) * 16 + lid;
                *(f16x4*)(hwp + row * 16 + (q & 1) * 8) = nh;
            }
            zc[0] = zn0;  zc[1] = zn1;

            if (i == 7 && c + 1 < nch) STAGE_WRITE((c + 1) & 1)
            __syncthreads();   // one barrier per step
        }
    }

    // ---- final: stash h, small output GEMM ----
    #pragma unroll
    for (int mtl = 0; mtl < 2; ++mtl)
        #pragma unroll
        for (int r = 0; r < 4; ++r)
            hfin[lid][(w * 2 + mtl) * 16 + q * 4 + r] = hf[mtl][r];
    __syncthreads();

    if (tid < 16 * COUT) {
        const int r = tid / COUT;
        const int cc = tid - r * COUT;
        float acc = D_b[cc];
        #pragma unroll 8
        for (int u = 0; u < NU; ++u)
            acc = fmaf(hfin[r][u], D_w[cc * NU + u], acc);
        out[((size_t)g * 16 + r) * COUT + cc] = acc;
    }
}

extern "C" void kernel_launch(void* const* d_in, const int* in_sizes, int n_in,
                              void* d_out, int out_size, void* d_ws, size_t ws_size,
                              hipStream_t stream)
{
    const float* x   = (const float*)d_in[0];
    const float* E_w = (const float*)d_in[1];
    const float* E_b = (const float*)d_in[2];
    const float* B_p = (const float*)d_in[3];
    const float* C_p = (const float*)d_in[4];
    const float* D_w = (const float*)d_in[5];
    const float* D_b = (const float*)d_in[6];
    float* out = (float*)d_out;

    const int B  = out_size / COUT;            // 512
    const int T  = in_sizes[0] / (B * DIN);    // 1024
    const int NB = B / 16;                     // 32 blocks

    rnn_core<<<NB, 256, 0, stream>>>(x, E_w, E_b, B_p, C_p, D_w, D_b, out, T);
}

// Round 7
// 598.037 us; speedup vs baseline: 1.5714x; 1.4753x over previous
//
#include <hip/hip_runtime.h>

#define EPS_C 0.01f
#define NU    128
#define DIN   64
#define COUT  10

typedef float    f32x4 __attribute__((ext_vector_type(4)));
typedef _Float16 f16x4 __attribute__((ext_vector_type(4)));
typedef _Float16 f16x8 __attribute__((ext_vector_type(8)));

#define MFMA32(A, B, C) __builtin_amdgcn_mfma_f32_16x16x32_f16((A), (B), (C), 0, 0, 0)
// LDS-only barrier: do NOT drain vmcnt -> x prefetch loads stay in flight
// across the per-step sync (the __syncthreads vmcnt(0) drain was the round-5/6
// dominator). h-exchange correctness needs lgkmcnt(0) only.
#define BAR() asm volatile("s_waitcnt lgkmcnt(0)\n\ts_barrier" ::: "memory")

// Transposed recurrence h^T(t+1) = h^T + eps*(A^T h^T + tanh(W^T h^T + z^T)),
// batch along MFMA n-dim (16 rows/block, 32 blocks). 8 waves (512 thr); wave w
// owns units u in [16w, 16w+16) = m-tile w.
// mfma_f32_16x16x32_f16 layouts (HW-verified rounds 3/5/6):
//   A-op: A[m = lane&15][k = quad*8 + j]
//   B-op: B[k = quad*8 + j][n = lane&15]
//   D   : D[row = quad*4 + reg][col = lane&15]
// h exchange: value u=16w+4q+r, b=lid -> hbuf[w>>1][(2(w&1)+(q>>1))*16+lid][(q&1)*4+r]
// (index algebra verified: reads are linear ds_read_b128, conflict-free).
__global__ __launch_bounds__(512, 1)
void rnn_core(const float* __restrict__ x,
              const float* __restrict__ E_w, const float* __restrict__ E_b,
              const float* __restrict__ B_p, const float* __restrict__ C_p,
              const float* __restrict__ D_w, const float* __restrict__ D_b,
              float* __restrict__ out, int T)
{
    const int tid  = threadIdx.x;
    const int lane = tid & 63;
    const int w    = tid >> 6;     // wave 0..7
    const int lid  = lane & 15;
    const int q    = lane >> 4;
    const int g    = blockIdx.x;   // batch group (16 rows)

    // xs[buf]: 16 steps of x in B-frag layout: [t16][kt2][lane64][8 halves]
    __shared__ _Float16 xs[2][16 * 2 * 64 * 8];   // 2 x 32 KB
    __shared__ _Float16 hbuf[2][4][64][8];        // [parity][kt][lane][j] 8 KB
    __shared__ float    hfin[16][NU + 4];

    // ---- one-time weight fragments (wave w: m = 16w + lid) ----
    f16x8 AT[4], WT[4], EF[2];
    f32x4 ebv;
    {
        const int m = w * 16 + lid;
        #pragma unroll
        for (int kt = 0; kt < 4; ++kt) {
            f16x8 fa, fw;
            #pragma unroll
            for (int j = 0; j < 8; ++j) {
                const int k  = kt * 32 + q * 8 + j;
                const float dg = (k == m) ? 0.01f : 0.0f;
                fa[j] = (_Float16)(B_p[k * NU + m] - 0.6f * B_p[m * NU + k] - dg);
                fw[j] = (_Float16)(C_p[k * NU + m] - 0.6f * C_p[m * NU + k] - dg);
            }
            AT[kt] = fa;  WT[kt] = fw;
        }
        #pragma unroll
        for (int kt = 0; kt < 2; ++kt) {
            f16x8 fe;
            #pragma unroll
            for (int j = 0; j < 8; ++j)
                fe[j] = (_Float16)E_w[m * DIN + kt * 32 + q * 8 + j];
            EF[kt] = fe;
        }
        #pragma unroll
        for (int r = 0; r < 4; ++r)
            ebv[r] = E_b[w * 16 + q * 4 + r];
    }

    // ---- x staging mapping (512 loader threads) ----
    // bb = batch row, s2 = d-quad (d = 4*s2..4*s2+3), tp = step parity
    const int bb = tid & 15;
    const int s2 = (tid >> 4) & 15;
    const int tp = tid >> 8;            // 0 or 1
    const float* xrow = x + ((size_t)(g * 16 + bb) * T) * DIN + s2 * 4;
    const int wb2 = (((s2 >> 3) * 64) + (((s2 >> 1) & 3) * 16) + bb) * 16 + (s2 & 1) * 8;

    float4 xg[8];   // 8 steps/thread (steps 2*i+tp of a chunk)

#define STAGE_WRITE(BUF)                                                      \
    {                                                                         \
        char* base_ = (char*)&xs[(BUF)][0];                                   \
        _Pragma("unroll")                                                     \
        for (int i2 = 0; i2 < 8; ++i2) {                                      \
            float4 v_ = xg[i2];                                               \
            f16x4 h4_;                                                        \
            h4_[0] = (_Float16)v_.x; h4_[1] = (_Float16)v_.y;                 \
            h4_[2] = (_Float16)v_.z; h4_[3] = (_Float16)v_.w;                 \
            *(f16x4*)(base_ + (2 * i2 + tp) * 2048 + wb2) = h4_;              \
        }                                                                     \
    }

    // ---- init: zero parity-0 h buffer; stage chunk 0 ----
    if (tid < 256)
        ((float4*)&hbuf[0][0][0][0])[tid] = (float4){0.f, 0.f, 0.f, 0.f};
    #pragma unroll
    for (int i = 0; i < 8; ++i)
        xg[i] = *(const float4*)(xrow + (size_t)(2 * i + tp) * DIN);
    STAGE_WRITE(0)
    __syncthreads();

    // ---- state init: h = 0, z_cur = z(0) ----
    f32x4 hf = {0.f, 0.f, 0.f, 0.f};
    f32x4 zc;
    {
        f16x8 x0 = *(const f16x8*)((char*)&xs[0][0] + (0 * 64 + lane) * 16);
        f16x8 x1 = *(const f16x8*)((char*)&xs[0][0] + (1 * 64 + lane) * 16);
        zc = ebv;
        zc = MFMA32(EF[0], x0, zc);
        zc = MFMA32(EF[1], x1, zc);
    }

    const int nch = T >> 4;   // 64 chunks of 16 steps
    for (int c = 0; c < nch; ++c) {
        if (c + 1 < nch) {
            const float* xr2 = xrow + (size_t)(c + 1) * 16 * DIN;
            #pragma unroll
            for (int i = 0; i < 8; ++i)
                xg[i] = *(const float4*)(xr2 + (size_t)(2 * i + tp) * DIN);
        }
        #pragma unroll
        for (int i = 0; i < 16; ++i) {
            const int t  = c * 16 + i;
            const int p  = i & 1;
            const int np = p ^ 1;

            // h B-frags for this step (linear ds_read_b128, conflict-free)
            f16x8 hB[4];
            #pragma unroll
            for (int kt = 0; kt < 4; ++kt)
                hB[kt] = *(const f16x8*)((char*)&hbuf[p][0][0][0] + (kt * 64 + lane) * 16);

            // x B-frags for t+1 (z_next, off critical path)
            int tt = t + 1; if (tt >= T) tt = T - 1;
            const int it = tt & 15;
            char* xb = (char*)&xs[(tt >> 4) & 1][0];
            f16x8 xfA = *(const f16x8*)(xb + ((it * 2 + 0) * 64 + lane) * 16);
            f16x8 xfB = *(const f16x8*)(xb + ((it * 2 + 1) * 64 + lane) * 16);

            // ---- on-path MFMAs: two depth-4 chains, interleaved ----
            f32x4 ya = {0.f, 0.f, 0.f, 0.f};
            f32x4 wa = zc;
            #pragma unroll
            for (int kt = 0; kt < 4; ++kt) {
                ya = MFMA32(AT[kt], hB[kt], ya);
                wa = MFMA32(WT[kt], hB[kt], wa);
            }

            // ---- epilogue: h += eps*(ya + tanh(wa)); D->B shuffled write ----
            {
                f16x4 nh;
                #pragma unroll
                for (int r = 0; r < 4; ++r) {
                    const float arg = wa[r];
                    const float e2  = __expf(2.0f * arg);
                    const float th  = 1.0f - 2.0f * __builtin_amdgcn_rcpf(e2 + 1.0f);
                    const float hv  = hf[r] + EPS_C * (ya[r] + th);
                    hf[r] = hv;
                    nh[r] = (_Float16)hv;
                }
                char* hwp = (char*)&hbuf[np][w >> 1][0][0];
                const int row = (2 * (w & 1) + (q >> 1)) * 16 + lid;
                *(f16x4*)(hwp + row * 16 + (q & 1) * 8) = nh;
            }

            // z(t+1): independent MFMAs issue while the barrier drains
            f32x4 zn = ebv;
            zn = MFMA32(EF[0], xfA, zn);
            zn = MFMA32(EF[1], xfB, zn);
            zc = zn;

            if (i == 13 && c + 1 < nch) STAGE_WRITE((c + 1) & 1)
            BAR();   // lgkmcnt(0) + s_barrier; vmcnt stays in flight
        }
    }

    // ---- final: stash h, small output GEMM ----
    #pragma unroll
    for (int r = 0; r < 4; ++r)
        hfin[lid][w * 16 + q * 4 + r] = hf[r];
    __syncthreads();

    if (tid < 16 * COUT) {
        const int r  = tid / COUT;
        const int cc = tid - r * COUT;
        float acc = D_b[cc];
        #pragma unroll 8
        for (int u = 0; u < NU; ++u)
            acc = fmaf(hfin[r][u], D_w[cc * NU + u], acc);
        out[((size_t)g * 16 + r) * COUT + cc] = acc;
    }
}

extern "C" void kernel_launch(void* const* d_in, const int* in_sizes, int n_in,
                              void* d_out, int out_size, void* d_ws, size_t ws_size,
                              hipStream_t stream)
{
    const float* x   = (const float*)d_in[0];
    const float* E_w = (const float*)d_in[1];
    const float* E_b = (const float*)d_in[2];
    const float* B_p = (const float*)d_in[3];
    const float* C_p = (const float*)d_in[4];
    const float* D_w = (const float*)d_in[5];
    const float* D_b = (const float*)d_in[6];
    float* out = (float*)d_out;

    const int B  = out_size / COUT;            // 512
    const int T  = in_sizes[0] / (B * DIN);    // 1024
    const int NB = B / 16;                     // 32 blocks

    rnn_core<<<NB, 512, 0, stream>>>(x, E_w, E_b, B_p, C_p, D_w, D_b, out, T);
}